// Round 2
// baseline (24871.414 us; speedup 1.0000x reference)
//
#include <hip/hip_runtime.h>

// RIM network, persistent 2-phase-per-step kernel for MI355X (gfx950).
// B=256,T=128,I=128,H=256,M=6,MPG=2,K=16,R=16,NH=4,TASK=32,SENS=96,O=64
//
//  X phase: block = (m = bid%6, 8-row batch chunk xc = bid/6)
//           gather A_comm(t-1) -> H_comm(t-1) -> outputs; then
//           inp (folded W, emu-fp32 MFMA) + A_in, rec (fp32), tanh, H_in; Q/K (emu-fp32).
//  Y phase: block = (head a, module n, d-half, 64-row chunk):
//           Vc = H_in @ W_V emu-fp32 MFMA, W_V (hi/lo) resident in LDS.
//           duties: attention weights (sigmoid+blend), out-projection(t-1) emu-fp32.
// Global barrier between phases (epoch counter in d_ws, zeroed per call).
// All magnitude-scaling matmuls use 3-product bf16 emulation (Ah*Bh+Al*Bh+Ah*Bl),
// rel err ~2e-5, because threshold is ~6e-5 relative to |out|max ~ 488.

#define NBLK 192
#define T_STEPS 128

typedef __attribute__((ext_vector_type(8))) short bf16x8;
typedef __attribute__((ext_vector_type(4))) float f32x4;

__device__ __forceinline__ unsigned short f2bf(float f){
  unsigned u = __float_as_uint(f);
  u += 0x7FFFu + ((u >> 16) & 1u);           // RNE
  return (unsigned short)(u >> 16);
}
__device__ __forceinline__ float bf2f(unsigned short h){
  return __uint_as_float(((unsigned)h) << 16);
}
__device__ __forceinline__ bf16x8 bzero8(){
  bf16x8 v;
#pragma unroll
  for (int i = 0; i < 8; ++i) v[i] = 0;
  return v;
}

struct Params {
  const float *x, *Wt, *Wsn, *Wip, *bip, *U, *Vlr, *bias, *WQ, *WK, *WV, *Wout, *bout;
  float *out0, *hid, *ain, *acm, *aww;
  unsigned short *WVhi, *WVlo, *WQKhi, *WQKlo, *Wfshi, *Wfslo, *Wins, *Wouthi, *Woutlo;
  unsigned short *Hhi, *Hlo;
  float *Qs, *Ks, *Vc;
  unsigned *bar;
};

// ---------------- prep: fold W_in @ Wip (fp32), swizzle into B-frag layout (hi/lo)
__global__ void prep_fold(Params p){
  int bid = blockIdx.x; int d = threadIdx.x;   // 256 blocks x 256 threads
  int m, i;
  if (bid < 32)       { m = 0; i = bid; }
  else if (bid < 64)  { m = 1; i = bid - 32; }
  else if (bid < 160) { m = 2; i = bid - 64; }
  else                { m = 3; i = bid - 160; }
  const float* wrow = (m < 2) ? (p.Wt + (m*32 + i)*256) : (p.Wsn + ((m-2)*96 + i)*256);
  const float* wip  = p.Wip + (long)m*256*256;
  float acc = 0.f;
  for (int h = 0; h < 256; ++h) acc += wrow[h] * wip[h*256 + d];
  int kt = i >> 5, j = i & 7, lane = ((i >> 3) & 3)*16 + (d & 15), nt = d >> 4;
  long off = (((long)(m*3 + kt)*16 + nt)*64 + lane)*8 + j;
  unsigned short hi = f2bf(acc);
  p.Wfshi[off] = hi;
  p.Wfslo[off] = f2bf(acc - bf2f(hi));
  p.Wins[off]  = f2bf(wrow[d]);
}

// ---------------- prep: swizzle W_V, W_Q|W_K, Wout^T into B-frag layout (hi/lo)
__global__ void prep_swz(Params p){
  int bid = blockIdx.x, tid = threadIdx.x;     // 241 blocks x 512 threads
  if (bid < 192){
    int a = bid/48, n = (bid/8)%6, kt = bid%8;
    const float* src = p.WV + ((long)(a*6+n)*256 + kt*32)*256;
    long dstBase = (((long)(a*6+n)*8 + kt)*16)*512;
    for (int e = tid; e < 8192; e += 512){
      int hl = e >> 8, d = e & 255;            // h = kt*32+hl
      float w = src[hl*256 + d];
      unsigned short hi = f2bf(w);
      unsigned short lo = f2bf(w - bf2f(hi));
      int lane = ((hl>>3)&3)*16 + (d&15), j = hl&7, nt = d>>4;
      long off = dstBase + ((long)nt*64 + lane)*8 + j;
      p.WVhi[off] = hi; p.WVlo[off] = lo;
    }
  } else if (bid < 240){
    int q2 = bid - 192; int m = q2/8, kt = q2%8;
    for (int e = tid; e < 4096; e += 512){
      int hl = e >> 7, c = e & 127;            // cols: [Q a0..3 | K a0..3] x16
      int isK = c >> 6, a = (c>>4)&3, q = c&15;
      const float* W = isK ? p.WK : p.WQ;
      float w = W[((long)(a*6+m)*256 + kt*32 + hl)*16 + q];
      int lane = ((hl>>3)&3)*16 + q, j = hl&7, nt = c>>4;
      long off = (((long)(m*8+kt)*8 + nt)*512) + (long)lane*8 + j;
      unsigned short hi = f2bf(w);
      p.WQKhi[off] = hi; p.WQKlo[off] = f2bf(w - bf2f(hi));
    }
  } else {
    for (int e = tid; e < 32768; e += 512){
      int o = e >> 9, kk = e & 511;
      float w = p.Wout[o*512 + kk];
      int kt = kk>>5, j = kk&7, lane = (((kk>>3)&3)<<4) + (o&15), nt = o>>4;
      long off = ((long)(kt*4+nt)*512) + lane*8 + j;
      unsigned short hi = f2bf(w);
      p.Wouthi[off] = hi; p.Woutlo[off] = f2bf(w - bf2f(hi));
    }
  }
}

// ---------------- global barrier (epoch based, cnt/rel zeroed per launch)
__device__ __forceinline__ void gbar(unsigned* cnt, unsigned* rel, unsigned ep){
  __syncthreads();
  if (threadIdx.x == 0){
    unsigned old = __hip_atomic_fetch_add(cnt, 1u, __ATOMIC_ACQ_REL, __HIP_MEMORY_SCOPE_AGENT);
    if (old == ep * (unsigned)NBLK - 1u){
      __hip_atomic_store(rel, ep, __ATOMIC_RELEASE, __HIP_MEMORY_SCOPE_AGENT);
    } else {
      unsigned v;
      do {
        __builtin_amdgcn_s_sleep(1);
        v = __hip_atomic_load(rel, __ATOMIC_ACQUIRE, __HIP_MEMORY_SCOPE_AGENT);
      } while (v < ep);
    }
  }
  __syncthreads();
  __threadfence();
}

// ---------------- main persistent kernel
__global__ __launch_bounds__(512) void rim_main(Params p){
  extern __shared__ char smem[];
  unsigned short* ldsW = (unsigned short*)smem;            // 131072 B  W_V slice (hi/lo)
  unsigned short* xs   = (unsigned short*)(smem + 131072); //   2048 B  x hi   [8][128] (xor-swz)
  unsigned short* xsl  = (unsigned short*)(smem + 133120); //   2048 B  x lo
  unsigned short* hs   = (unsigned short*)(smem + 135168); //   4096 B  H_in hi [8][256] (xor-swz)
  unsigned short* hsl  = (unsigned short*)(smem + 139264); //   4096 B  H_in lo
  float* inpS          = (float*)(smem + 143360);          //   8192 B  inp    [8][256] f32
  float* hcS           = (float*)(smem + 151552);          //   8192 B  H_comm [8][256] f32
  float* rS            = (float*)(smem + 159744);          //    512 B  r      [8][16]  f32

  const int tid = threadIdx.x, bid = blockIdx.x;
  const int lane = tid & 63, wv = tid >> 6;
  const int d = tid & 255, g = tid >> 8;
  // X role
  const int xm = bid % 6, xc = bid / 6;
  // Y role
  const int ya = bid & 3; int yr1 = bid >> 2;
  const int yn = yr1 % 6; int yr2 = yr1 / 6;
  const int ydh = yr2 & 1, yc = yr2 >> 1;
  const int ych = yr2;

  unsigned* cnt = p.bar;
  unsigned* rel = p.bar + 32;

  // ---- load this block's W_V slice (hi+lo, 128 KB) into LDS, once ----
  for (int it = 0; it < 16; ++it){
    int q = it*8 + wv;                                     // 128 chunks of 1KB
    int kt = q >> 4, ntl = (q >> 1) & 7, pp = q & 1;
    const unsigned short* src = (pp ? p.WVlo : p.WVhi)
        + ((((long)(ya*6 + yn)*8 + kt)*16 + (ydh*8 + ntl))*64)*8;
    ((int4*)(smem + q*1024))[lane] = ((const int4*)src)[lane];
  }
  __syncthreads();

  float hin[4] = {0.f, 0.f, 0.f, 0.f};
  float hc[4];
  unsigned ep = 0;

  for (int t = 0; t <= T_STEPS; ++t){
    // ================= X phase =================
    if (t > 0){
#pragma unroll
      for (int k = 0; k < 4; ++k){
        int b = xc*8 + g*4 + k;
        float acc = 0.f;
#pragma unroll
        for (int a = 0; a < 4; ++a){
          const float* awr = p.aww + ((((long)a*T_STEPS + (t-1))*256 + b)*6 + xm)*6;
          const float* vcr = p.Vc + ((long)(a*256 + b)*6)*256 + d;
#pragma unroll
          for (int n = 0; n < 6; ++n) acc += awr[n] * vcr[n*256];
        }
        float hcm = hin[k] + acc;
        hc[k] = hcm;
        long o = ((long)(b*T_STEPS + (t-1))*6 + xm)*256 + d;
        p.hid[o] = hcm;
        p.acm[o] = acc;
      }
    } else {
      hc[0] = hc[1] = hc[2] = hc[3] = 0.f;
    }

    if (t < T_STEPS){
      if (xm >= 4){
#pragma unroll
        for (int k = 0; k < 4; ++k){
          int b = xc*8 + g*4 + k;
          p.ain[((long)(b*T_STEPS + t)*6 + xm)*256 + d] = 0.f;
        }
      }
      // stage x (bf16 hi/lo, xor-swizzled rows)
      {
#pragma unroll
        for (int h2 = 0; h2 < 2; ++h2){
          int i0 = tid + h2*512;
          int r0 = i0 >> 7, c0 = i0 & 127;
          float v = p.x[((long)(xc*8 + r0)*T_STEPS + t)*128 + c0];
          unsigned short hi = f2bf(v);
          int idx = r0*128 + (c0 ^ ((r0&7)<<3));
          xs[idx]  = hi;
          xsl[idx] = f2bf(v - bf2f(hi));
        }
      }
      __syncthreads();
      // A_in (single bf16) + inp (emu-fp32) via MFMA (modules 0..3)
      if (xm < 4){
        int nkt = (xm < 2) ? 1 : 3;
        int kbase = (xm < 2) ? 96 : 0;
#pragma unroll
        for (int half = 0; half < 2; ++half){
          int nt = wv*2 + half;
          f32x4 cin = {0.f,0.f,0.f,0.f}, cf = {0.f,0.f,0.f,0.f};
          for (int kt = 0; kt < nkt; ++kt){
            bf16x8 ah = bzero8(), al = bzero8();
            int r = lane & 15;
            if (r < 8){
              int kk = kbase + kt*32 + ((lane>>4)<<3);
              int idx = r*128 + (kk ^ ((r&7)<<3));
              ah = *(const bf16x8*)&xs[idx];
              al = *(const bf16x8*)&xsl[idx];
            }
            long boff = (((long)(xm*3 + kt)*16 + nt)*64 + lane)*8;
            bf16x8 bi = *(const bf16x8*)(p.Wins  + boff);
            bf16x8 bh = *(const bf16x8*)(p.Wfshi + boff);
            bf16x8 bl = *(const bf16x8*)(p.Wfslo + boff);
            cin = __builtin_amdgcn_mfma_f32_16x16x32_bf16(ah, bi, cin, 0, 0, 0);
            cf  = __builtin_amdgcn_mfma_f32_16x16x32_bf16(ah, bh, cf , 0, 0, 0);
            cf  = __builtin_amdgcn_mfma_f32_16x16x32_bf16(al, bh, cf , 0, 0, 0);
            cf  = __builtin_amdgcn_mfma_f32_16x16x32_bf16(ah, bl, cf , 0, 0, 0);
          }
          int col = nt*16 + (lane & 15);
#pragma unroll
          for (int i = 0; i < 4; ++i){
            int r = ((lane>>4)<<2) + i;
            if (r < 8){
              int b = xc*8 + r;
              p.ain[((long)(b*T_STEPS + t)*6 + xm)*256 + col] = cin[i];
              inpS[r*256 + col] = cf[i];
            }
          }
        }
      }
      __syncthreads();
      // stage H_comm(t-1) for rec
#pragma unroll
      for (int k = 0; k < 4; ++k) hcS[(g*4 + k)*256 + d] = hc[k];
      __syncthreads();
      // rec part 1: r[b][q] = sum_h Hc[b][h] U[m][h][q]  (fp32)
      {
        int bl = tid >> 6, q = (tid >> 2) & 15, part = tid & 3;
        const float* up = p.U + (long)xm*256*16 + q;
        float s = 0.f;
        int d0 = part*64;
        for (int dd = 0; dd < 64; ++dd) s += hcS[bl*256 + d0 + dd] * up[(d0 + dd)*16];
        s += __shfl_down(s, 1);
        s += __shfl_down(s, 2);
        if (part == 0) rS[bl*16 + q] = s;
      }
      __syncthreads();
      // H_in = tanh(inp + rec + bip + bias); stash bf16 hi/lo
#pragma unroll
      for (int k = 0; k < 4; ++k){
        int bl = g*4 + k;
        float pre = p.bip[xm*256 + d] + p.bias[xm*256 + d];
        if (xm < 4) pre += inpS[bl*256 + d];
        const float* vl = p.Vlr + (long)xm*16*256 + d;
#pragma unroll
        for (int q = 0; q < 16; ++q) pre += rS[bl*16 + q] * vl[q*256];
        float h = tanhf(pre);
        hin[k] = h;
        unsigned short hi = f2bf(h);
        unsigned short lo = f2bf(h - bf2f(hi));
        int b = xc*8 + bl;
        long ho = ((long)xm*256 + b)*256 + d;
        p.Hhi[ho] = hi; p.Hlo[ho] = lo;
        int idx = bl*256 + (d ^ ((bl&7)<<3));
        hs[idx] = hi; hsl[idx] = lo;
      }
      __syncthreads();
      // Q/K via MFMA (emu-fp32): cols = [Q a0..3 | K a0..3] x 16
      {
        int nt = wv;
        f32x4 c = {0.f,0.f,0.f,0.f};
#pragma unroll
        for (int kt = 0; kt < 8; ++kt){
          bf16x8 ah = bzero8(), al = bzero8();
          int r = lane & 15;
          if (r < 8){
            int kk = kt*32 + ((lane>>4)<<3);
            int idx = r*256 + (kk ^ ((r&7)<<3));
            ah = *(const bf16x8*)&hs[idx];
            al = *(const bf16x8*)&hsl[idx];
          }
          long bo = (((long)(xm*8 + kt)*8 + nt)*64 + lane)*8;
          bf16x8 bh = *(const bf16x8*)(p.WQKhi + bo);
          bf16x8 bl = *(const bf16x8*)(p.WQKlo + bo);
          c = __builtin_amdgcn_mfma_f32_16x16x32_bf16(ah, bh, c, 0, 0, 0);
          c = __builtin_amdgcn_mfma_f32_16x16x32_bf16(al, bh, c, 0, 0, 0);
          c = __builtin_amdgcn_mfma_f32_16x16x32_bf16(ah, bl, c, 0, 0, 0);
        }
        float* dst = (nt < 4) ? p.Qs : p.Ks;
        int a = nt & 3, q = lane & 15;
#pragma unroll
        for (int i = 0; i < 4; ++i){
          int r = ((lane>>4)<<2) + i;
          if (r < 8){
            int b = xc*8 + r;
            dst[((long)(a*256 + b)*6 + xm)*16 + q] = c[i];
          }
        }
      }
    }

    gbar(cnt, rel, ++ep);

    // ================= Y phase =================
    if (t < T_STEPS){
      // Vc = H_in @ W_V, emu-fp32
      {
        int nt = wv;
        f32x4 C[4];
#pragma unroll
        for (int rt = 0; rt < 4; ++rt) C[rt] = (f32x4){0.f,0.f,0.f,0.f};
#pragma unroll
        for (int kt = 0; kt < 8; ++kt){
          bf16x8 Ah[4], Al[4];
#pragma unroll
          for (int rt = 0; rt < 4; ++rt){
            int b = yc*64 + rt*16 + (lane & 15);
            long off = ((long)yn*256 + b)*256 + kt*32 + ((lane>>4)<<3);
            Ah[rt] = *(const bf16x8*)(p.Hhi + off);
            Al[rt] = *(const bf16x8*)(p.Hlo + off);
          }
          bf16x8 Bh = *(const bf16x8*)&ldsW[(((kt*8 + nt)*2 + 0)*64 + lane)*8];
          bf16x8 Bl = *(const bf16x8*)&ldsW[(((kt*8 + nt)*2 + 1)*64 + lane)*8];
#pragma unroll
          for (int rt = 0; rt < 4; ++rt){
            C[rt] = __builtin_amdgcn_mfma_f32_16x16x32_bf16(Ah[rt], Bh, C[rt], 0, 0, 0);
            C[rt] = __builtin_amdgcn_mfma_f32_16x16x32_bf16(Al[rt], Bh, C[rt], 0, 0, 0);
            C[rt] = __builtin_amdgcn_mfma_f32_16x16x32_bf16(Ah[rt], Bl, C[rt], 0, 0, 0);
          }
        }
        int dcol = ydh*128 + nt*16 + (lane & 15);
#pragma unroll
        for (int rt = 0; rt < 4; ++rt){
#pragma unroll
          for (int i = 0; i < 4; ++i){
            int b = yc*64 + rt*16 + ((lane>>4)<<2) + i;
            p.Vc[((long)(ya*256 + b)*6 + yn)*256 + dcol] = C[rt][i];
          }
        }
      }
      // attention weights (duty: yn==0 blocks)
      if (yn == 0 && lane < 36){
        int m = lane / 6, n2 = lane % 6;
#pragma unroll
        for (int bb = 0; bb < 4; ++bb){
          int b = ych*32 + wv*4 + bb;
          const float* qp = p.Qs + ((long)(ya*256 + b)*6 + m)*16;
          const float* kp = p.Ks + ((long)(ya*256 + b)*6 + n2)*16;
          float dot = 0.f;
#pragma unroll
          for (int q = 0; q < 16; ++q) dot += qp[q]*kp[q];
          float s = 1.f / (1.f + expf(-dot*0.25f));
          long ob = (((long)ya*T_STEPS + t)*256 + b)*36 + m*6 + n2;
          if (t > 0) s = 0.5f*s + 0.5f*p.aww[ob - 256*36];
          p.aww[ob] = s;
        }
      }
    }
    // out projection for step t-1 (duty: ya==0,yn==1; emu-fp32, A from p.hid)
    if (t > 0 && ya == 0 && yn == 1){
      int rt = wv >> 2, nt = wv & 3;
      int rb = ych*32;
      f32x4 c = {0.f,0.f,0.f,0.f};
      for (int kt = 0; kt < 16; ++kt){
        int b = rb + rt*16 + (lane & 15);
        int kk = kt*32 + ((lane>>4)<<3);        // 0..511
        int m45 = kk >> 8, dd = kk & 255;
        const float* hp = p.hid + ((long)(b*T_STEPS + (t-1))*6 + 4 + m45)*256 + dd;
        bf16x8 ah, al;
#pragma unroll
        for (int j = 0; j < 8; ++j){
          float v = hp[j];
          unsigned short hi = f2bf(v);
          ah[j] = (short)hi;
          al[j] = (short)f2bf(v - bf2f(hi));
        }
        long bo = ((long)(kt*4 + nt)*512) + (long)lane*8;
        bf16x8 bh = *(const bf16x8*)(p.Wouthi + bo);
        bf16x8 bl = *(const bf16x8*)(p.Woutlo + bo);
        c = __builtin_amdgcn_mfma_f32_16x16x32_bf16(ah, bh, c, 0, 0, 0);
        c = __builtin_amdgcn_mfma_f32_16x16x32_bf16(al, bh, c, 0, 0, 0);
        c = __builtin_amdgcn_mfma_f32_16x16x32_bf16(ah, bl, c, 0, 0, 0);
      }
      int o = nt*16 + (lane & 15);
      float bo = p.bout[o];
#pragma unroll
      for (int i = 0; i < 4; ++i){
        int b = rb + rt*16 + ((lane>>4)<<2) + i;
        p.out0[((long)b*T_STEPS + (t-1))*64 + o] = c[i] + bo;
      }
    }

    if (t < T_STEPS) gbar(cnt, rel, ++ep);
  }
}

extern "C" void kernel_launch(void* const* d_in, const int* in_sizes, int n_in,
                              void* d_out, int out_size, void* d_ws, size_t ws_size,
                              hipStream_t stream) {
  (void)in_sizes; (void)n_in; (void)out_size;
  if (ws_size < 16450560) return;

  Params p;
  p.x    = (const float*)d_in[0];
  p.Wt   = (const float*)d_in[1];
  p.Wsn  = (const float*)d_in[2];
  p.Wip  = (const float*)d_in[3];
  p.bip  = (const float*)d_in[4];
  p.U    = (const float*)d_in[5];
  p.Vlr  = (const float*)d_in[6];
  p.bias = (const float*)d_in[7];
  p.WQ   = (const float*)d_in[8];
  p.WK   = (const float*)d_in[9];
  p.WV   = (const float*)d_in[10];
  p.Wout = (const float*)d_in[11];
  p.bout = (const float*)d_in[12];

  float* out = (float*)d_out;
  p.out0 = out;                    // (B,T,O)
  p.hid  = out + 2097152;          // (B,T,M,H)
  p.ain  = out + 52428800;         // (B,T,M,H)
  p.acm  = out + 102760448;        // (B,T,M,H)
  p.aww  = out + 153092096;        // (NH,T,B,M,M)

  char* ws = (char*)d_ws;
  p.bar    = (unsigned*)ws;                         //        0,     1024
  p.WVhi   = (unsigned short*)(ws + 1024);          //  3145728
  p.WVlo   = (unsigned short*)(ws + 3146752);       //  3145728
  p.WQKhi  = (unsigned short*)(ws + 6292480);       //   393216
  p.WQKlo  = (unsigned short*)(ws + 6685696);       //   393216
  p.Wfshi  = (unsigned short*)(ws + 7078912);       //   196608
  p.Wfslo  = (unsigned short*)(ws + 7275520);       //   196608
  p.Wins   = (unsigned short*)(ws + 7472128);       //   196608
  p.Wouthi = (unsigned short*)(ws + 7668736);       //    65536
  p.Woutlo = (unsigned short*)(ws + 7734272);       //    65536
  p.Hhi    = (unsigned short*)(ws + 7799808);       //   786432
  p.Hlo    = (unsigned short*)(ws + 8586240);       //   786432
  p.Qs     = (float*)(ws + 9372672);                //   393216
  p.Ks     = (float*)(ws + 9765888);                //   393216
  p.Vc     = (float*)(ws + 10159104);               //  6291456 -> 16450560

  hipMemsetAsync(d_ws, 0, 1024, stream);
  hipLaunchKernelGGL(prep_fold, dim3(256), dim3(256), 0, stream, p);
  hipLaunchKernelGGL(prep_swz,  dim3(241), dim3(512), 0, stream, p);

  hipFuncSetAttribute((const void*)rim_main,
                      hipFuncAttributeMaxDynamicSharedMemorySize, 160256);
  hipLaunchKernelGGL(rim_main, dim3(NBLK), dim3(512), 160256, stream, p);
}

// Round 3
// 13189.145 us; speedup vs baseline: 1.8857x; 1.8857x over previous
//
#include <hip/hip_runtime.h>

// RIM network, persistent 2-phase-per-step kernel for MI355X (gfx950).
// B=256,T=128,I=128,H=256,M=6,MPG=2,K=16,R=16,NH=4,TASK=32,SENS=96,O=64
//
//  X phase: block = (module xm, 8-row batch chunk xc) [same-xc blocks share XCD]
//  Y phase: block = (head ya, module yn, d-half ydh, 64-row chunk yc)
//           [blocks sharing H_in rows share XCD]
// Global barrier between phases: relaxed spin + single release/acquire agent
// fences (one wbL2 + one invL2 per block per barrier — NOT per poll iteration;
// acquire-per-poll was a full-L2 invalidate storm, 97us/phase in round 2).

#define NBLK 192
#define T_STEPS 128

typedef __attribute__((ext_vector_type(8))) short bf16x8;
typedef __attribute__((ext_vector_type(4))) float f32x4;

__device__ __forceinline__ unsigned short f2bf(float f){
  unsigned u = __float_as_uint(f);
  u += 0x7FFFu + ((u >> 16) & 1u);           // RNE
  return (unsigned short)(u >> 16);
}
__device__ __forceinline__ float bf2f(unsigned short h){
  return __uint_as_float(((unsigned)h) << 16);
}
__device__ __forceinline__ bf16x8 bzero8(){
  bf16x8 v;
#pragma unroll
  for (int i = 0; i < 8; ++i) v[i] = 0;
  return v;
}

struct Params {
  const float *x, *Wt, *Wsn, *Wip, *bip, *U, *Vlr, *bias, *WQ, *WK, *WV, *Wout, *bout;
  float *out0, *hid, *ain, *acm, *aww;
  unsigned short *WVhi, *WVlo, *WQKhi, *WQKlo, *Wfshi, *Wfslo, *Wins, *Wouthi, *Woutlo;
  unsigned short *Hhi, *Hlo;
  float *Qs, *Ks, *Vc;
  unsigned *bar;
};

// ---------------- prep: fold W_in @ Wip (fp32), swizzle into B-frag layout (hi/lo)
__global__ void prep_fold(Params p){
  int bid = blockIdx.x; int d = threadIdx.x;   // 256 blocks x 256 threads
  int m, i;
  if (bid < 32)       { m = 0; i = bid; }
  else if (bid < 64)  { m = 1; i = bid - 32; }
  else if (bid < 160) { m = 2; i = bid - 64; }
  else                { m = 3; i = bid - 160; }
  const float* wrow = (m < 2) ? (p.Wt + (m*32 + i)*256) : (p.Wsn + ((m-2)*96 + i)*256);
  const float* wip  = p.Wip + (long)m*256*256;
  float acc = 0.f;
  for (int h = 0; h < 256; ++h) acc += wrow[h] * wip[h*256 + d];
  int kt = i >> 5, j = i & 7, lane = ((i >> 3) & 3)*16 + (d & 15), nt = d >> 4;
  long off = (((long)(m*3 + kt)*16 + nt)*64 + lane)*8 + j;
  unsigned short hi = f2bf(acc);
  p.Wfshi[off] = hi;
  p.Wfslo[off] = f2bf(acc - bf2f(hi));
  p.Wins[off]  = f2bf(wrow[d]);
}

// ---------------- prep: swizzle W_V, W_Q|W_K, Wout^T into B-frag layout (hi/lo)
__global__ void prep_swz(Params p){
  int bid = blockIdx.x, tid = threadIdx.x;     // 241 blocks x 512 threads
  if (bid < 192){
    int a = bid/48, n = (bid/8)%6, kt = bid%8;
    const float* src = p.WV + ((long)(a*6+n)*256 + kt*32)*256;
    long dstBase = (((long)(a*6+n)*8 + kt)*16)*512;
    for (int e = tid; e < 8192; e += 512){
      int hl = e >> 8, d = e & 255;            // h = kt*32+hl
      float w = src[hl*256 + d];
      unsigned short hi = f2bf(w);
      unsigned short lo = f2bf(w - bf2f(hi));
      int lane = ((hl>>3)&3)*16 + (d&15), j = hl&7, nt = d>>4;
      long off = dstBase + ((long)nt*64 + lane)*8 + j;
      p.WVhi[off] = hi; p.WVlo[off] = lo;
    }
  } else if (bid < 240){
    int q2 = bid - 192; int m = q2/8, kt = q2%8;
    for (int e = tid; e < 4096; e += 512){
      int hl = e >> 7, c = e & 127;            // cols: [Q a0..3 | K a0..3] x16
      int isK = c >> 6, a = (c>>4)&3, q = c&15;
      const float* W = isK ? p.WK : p.WQ;
      float w = W[((long)(a*6+m)*256 + kt*32 + hl)*16 + q];
      int lane = ((hl>>3)&3)*16 + q, j = hl&7, nt = c>>4;
      long off = (((long)(m*8+kt)*8 + nt)*512) + (long)lane*8 + j;
      unsigned short hi = f2bf(w);
      p.WQKhi[off] = hi; p.WQKlo[off] = f2bf(w - bf2f(hi));
    }
  } else {
    for (int e = tid; e < 32768; e += 512){
      int o = e >> 9, kk = e & 511;
      float w = p.Wout[o*512 + kk];
      int kt = kk>>5, j = kk&7, lane = (((kk>>3)&3)<<4) + (o&15), nt = o>>4;
      long off = ((long)(kt*4+nt)*512) + lane*8 + j;
      unsigned short hi = f2bf(w);
      p.Wouthi[off] = hi; p.Woutlo[off] = f2bf(w - bf2f(hi));
    }
  }
}

// ---------------- global barrier: relaxed spin, one wbL2 + one invL2 per block
__device__ __forceinline__ void gbar(unsigned* cnt, unsigned* rel, unsigned ep){
  __syncthreads();
  if (threadIdx.x == 0){
    __builtin_amdgcn_fence(__ATOMIC_RELEASE, "agent");   // wb L2 (data -> coherence pt)
    unsigned old = __hip_atomic_fetch_add(cnt, 1u, __ATOMIC_RELAXED, __HIP_MEMORY_SCOPE_AGENT);
    if (old == ep * (unsigned)NBLK - 1u){
      __hip_atomic_store(rel, ep, __ATOMIC_RELAXED, __HIP_MEMORY_SCOPE_AGENT);
    } else {
      while (__hip_atomic_load(rel, __ATOMIC_RELAXED, __HIP_MEMORY_SCOPE_AGENT) < ep)
        __builtin_amdgcn_s_sleep(8);
    }
    __builtin_amdgcn_fence(__ATOMIC_ACQUIRE, "agent");   // inv L1+L2 once
  }
  __syncthreads();
}

// ---------------- main persistent kernel
__global__ __launch_bounds__(512) void rim_main(Params p){
  extern __shared__ char smem[];
  unsigned short* ldsW = (unsigned short*)smem;            // 131072 B  W_V slice (hi/lo)
  unsigned short* xs   = (unsigned short*)(smem + 131072); //   2048 B  x hi   [8][128] (xor-swz)
  unsigned short* xsl  = (unsigned short*)(smem + 133120); //   2048 B  x lo
  unsigned short* hs   = (unsigned short*)(smem + 135168); //   4096 B  H_in hi [8][256] (xor-swz)
  unsigned short* hsl  = (unsigned short*)(smem + 139264); //   4096 B  H_in lo
  float* inpS          = (float*)(smem + 143360);          //   8192 B  inp    [8][256] f32
  float* hcS           = (float*)(smem + 151552);          //   8192 B  H_comm [8][256] f32
  float* rS            = (float*)(smem + 159744);          //    512 B  r      [8][16]  f32

  const int tid = threadIdx.x, bid = blockIdx.x;
  const int lane = tid & 63, wv = tid >> 6;
  const int d = tid & 255, g = tid >> 8;

  // X role: all 6 modules of a batch-chunk on the same XCD (bid%8)
  const int xcdX = bid & 7, xslot = bid >> 3;              // slot 0..23
  const int xm = xslot % 6, xci = xslot / 6;               // xci 0..3
  const int xc = xcdX * 4 + xci;                           // 8-row chunk 0..31

  // Y role: the 8 (ya,ydh) blocks sharing an H_in row-slice on the same XCD
  const int xcdY = bid & 7, yslot = bid >> 3;              // 0..23
  const int yg = xcdY + 8 * (yslot >> 3);                  // group 0..23 = (yn,yc)
  const int yi = yslot & 7;
  const int yn = yg % 6, yc = yg / 6;                      // module, 64-row chunk
  const int ydh = yi >> 2, ya = yi & 3;                    // d-half, head
  const int ych = yc * 2 + ydh;                            // 32-row chunk 0..7 (duties)

  unsigned* cnt = p.bar;
  unsigned* rel = p.bar + 32;

  // ---- load this block's W_V slice (hi+lo, 128 KB) into LDS, once ----
  for (int it = 0; it < 16; ++it){
    int q = it*8 + wv;                                     // 128 chunks of 1KB
    int kt = q >> 4, ntl = (q >> 1) & 7, pp = q & 1;
    const unsigned short* src = (pp ? p.WVlo : p.WVhi)
        + ((((long)(ya*6 + yn)*8 + kt)*16 + (ydh*8 + ntl))*64)*8;
    ((int4*)(smem + q*1024))[lane] = ((const int4*)src)[lane];
  }
  __syncthreads();

  float hin[4] = {0.f, 0.f, 0.f, 0.f};
  float hc[4];
  unsigned ep = 0;

  for (int t = 0; t <= T_STEPS; ++t){
    // ================= X phase =================
    if (t > 0){
#pragma unroll
      for (int k = 0; k < 4; ++k){
        int b = xc*8 + g*4 + k;
        float acc = 0.f;
#pragma unroll
        for (int a = 0; a < 4; ++a){
          const float* awr = p.aww + ((((long)a*T_STEPS + (t-1))*256 + b)*6 + xm)*6;
          const float* vcr = p.Vc + ((long)(a*256 + b)*6)*256 + d;
#pragma unroll
          for (int n = 0; n < 6; ++n) acc += awr[n] * vcr[n*256];
        }
        float hcm = hin[k] + acc;
        hc[k] = hcm;
        long o = ((long)(b*T_STEPS + (t-1))*6 + xm)*256 + d;
        p.hid[o] = hcm;
        p.acm[o] = acc;
      }
    } else {
      hc[0] = hc[1] = hc[2] = hc[3] = 0.f;
    }

    if (t < T_STEPS){
      if (xm >= 4){
#pragma unroll
        for (int k = 0; k < 4; ++k){
          int b = xc*8 + g*4 + k;
          p.ain[((long)(b*T_STEPS + t)*6 + xm)*256 + d] = 0.f;
        }
      }
      // stage x (bf16 hi/lo, xor-swizzled rows)
      {
#pragma unroll
        for (int h2 = 0; h2 < 2; ++h2){
          int i0 = tid + h2*512;
          int r0 = i0 >> 7, c0 = i0 & 127;
          float v = p.x[((long)(xc*8 + r0)*T_STEPS + t)*128 + c0];
          unsigned short hi = f2bf(v);
          int idx = r0*128 + (c0 ^ ((r0&7)<<3));
          xs[idx]  = hi;
          xsl[idx] = f2bf(v - bf2f(hi));
        }
      }
      __syncthreads();
      // A_in (single bf16) + inp (emu-fp32) via MFMA (modules 0..3)
      if (xm < 4){
        int nkt = (xm < 2) ? 1 : 3;
        int kbase = (xm < 2) ? 96 : 0;
#pragma unroll
        for (int half = 0; half < 2; ++half){
          int nt = wv*2 + half;
          f32x4 cin = {0.f,0.f,0.f,0.f}, cf = {0.f,0.f,0.f,0.f};
          for (int kt = 0; kt < nkt; ++kt){
            bf16x8 ah = bzero8(), al = bzero8();
            int r = lane & 15;
            if (r < 8){
              int kk = kbase + kt*32 + ((lane>>4)<<3);
              int idx = r*128 + (kk ^ ((r&7)<<3));
              ah = *(const bf16x8*)&xs[idx];
              al = *(const bf16x8*)&xsl[idx];
            }
            long boff = (((long)(xm*3 + kt)*16 + nt)*64 + lane)*8;
            bf16x8 bi = *(const bf16x8*)(p.Wins  + boff);
            bf16x8 bh = *(const bf16x8*)(p.Wfshi + boff);
            bf16x8 bl = *(const bf16x8*)(p.Wfslo + boff);
            cin = __builtin_amdgcn_mfma_f32_16x16x32_bf16(ah, bi, cin, 0, 0, 0);
            cf  = __builtin_amdgcn_mfma_f32_16x16x32_bf16(ah, bh, cf , 0, 0, 0);
            cf  = __builtin_amdgcn_mfma_f32_16x16x32_bf16(al, bh, cf , 0, 0, 0);
            cf  = __builtin_amdgcn_mfma_f32_16x16x32_bf16(ah, bl, cf , 0, 0, 0);
          }
          int col = nt*16 + (lane & 15);
#pragma unroll
          for (int i = 0; i < 4; ++i){
            int r = ((lane>>4)<<2) + i;
            if (r < 8){
              int b = xc*8 + r;
              p.ain[((long)(b*T_STEPS + t)*6 + xm)*256 + col] = cin[i];
              inpS[r*256 + col] = cf[i];
            }
          }
        }
      }
      __syncthreads();
      // stage H_comm(t-1) for rec
#pragma unroll
      for (int k = 0; k < 4; ++k) hcS[(g*4 + k)*256 + d] = hc[k];
      __syncthreads();
      // rec part 1: r[b][q] = sum_h Hc[b][h] U[m][h][q]  (fp32)
      {
        int bl = tid >> 6, q = (tid >> 2) & 15, part = tid & 3;
        const float* up = p.U + (long)xm*256*16 + q;
        float s = 0.f;
        int d0 = part*64;
        for (int dd = 0; dd < 64; ++dd) s += hcS[bl*256 + d0 + dd] * up[(d0 + dd)*16];
        s += __shfl_down(s, 1);
        s += __shfl_down(s, 2);
        if (part == 0) rS[bl*16 + q] = s;
      }
      __syncthreads();
      // H_in = tanh(inp + rec + bip + bias); stash bf16 hi/lo
#pragma unroll
      for (int k = 0; k < 4; ++k){
        int bl = g*4 + k;
        float pre = p.bip[xm*256 + d] + p.bias[xm*256 + d];
        if (xm < 4) pre += inpS[bl*256 + d];
        const float* vl = p.Vlr + (long)xm*16*256 + d;
#pragma unroll
        for (int q = 0; q < 16; ++q) pre += rS[bl*16 + q] * vl[q*256];
        float h = tanhf(pre);
        hin[k] = h;
        unsigned short hi = f2bf(h);
        unsigned short lo = f2bf(h - bf2f(hi));
        int b = xc*8 + bl;
        long ho = ((long)xm*256 + b)*256 + d;
        p.Hhi[ho] = hi; p.Hlo[ho] = lo;
        int idx = bl*256 + (d ^ ((bl&7)<<3));
        hs[idx] = hi; hsl[idx] = lo;
      }
      __syncthreads();
      // Q/K via MFMA (emu-fp32): cols = [Q a0..3 | K a0..3] x 16
      {
        int nt = wv;
        f32x4 c = {0.f,0.f,0.f,0.f};
#pragma unroll
        for (int kt = 0; kt < 8; ++kt){
          bf16x8 ah = bzero8(), al = bzero8();
          int r = lane & 15;
          if (r < 8){
            int kk = kt*32 + ((lane>>4)<<3);
            int idx = r*256 + (kk ^ ((r&7)<<3));
            ah = *(const bf16x8*)&hs[idx];
            al = *(const bf16x8*)&hsl[idx];
          }
          long bo = (((long)(xm*8 + kt)*8 + nt)*64 + lane)*8;
          bf16x8 bh = *(const bf16x8*)(p.WQKhi + bo);
          bf16x8 bl = *(const bf16x8*)(p.WQKlo + bo);
          c = __builtin_amdgcn_mfma_f32_16x16x32_bf16(ah, bh, c, 0, 0, 0);
          c = __builtin_amdgcn_mfma_f32_16x16x32_bf16(al, bh, c, 0, 0, 0);
          c = __builtin_amdgcn_mfma_f32_16x16x32_bf16(ah, bl, c, 0, 0, 0);
        }
        float* dst = (nt < 4) ? p.Qs : p.Ks;
        int a = nt & 3, q = lane & 15;
#pragma unroll
        for (int i = 0; i < 4; ++i){
          int r = ((lane>>4)<<2) + i;
          if (r < 8){
            int b = xc*8 + r;
            dst[((long)(a*256 + b)*6 + xm)*16 + q] = c[i];
          }
        }
      }
    }

    gbar(cnt, rel, ++ep);

    // ================= Y phase =================
    if (t < T_STEPS){
      // Vc = H_in @ W_V, emu-fp32
      {
        int nt = wv;
        f32x4 C[4];
#pragma unroll
        for (int rt = 0; rt < 4; ++rt) C[rt] = (f32x4){0.f,0.f,0.f,0.f};
#pragma unroll
        for (int kt = 0; kt < 8; ++kt){
          bf16x8 Ah[4], Al[4];
#pragma unroll
          for (int rt = 0; rt < 4; ++rt){
            int b = yc*64 + rt*16 + (lane & 15);
            long off = ((long)yn*256 + b)*256 + kt*32 + ((lane>>4)<<3);
            Ah[rt] = *(const bf16x8*)(p.Hhi + off);
            Al[rt] = *(const bf16x8*)(p.Hlo + off);
          }
          bf16x8 Bh = *(const bf16x8*)&ldsW[(((kt*8 + nt)*2 + 0)*64 + lane)*8];
          bf16x8 Bl = *(const bf16x8*)&ldsW[(((kt*8 + nt)*2 + 1)*64 + lane)*8];
#pragma unroll
          for (int rt = 0; rt < 4; ++rt){
            C[rt] = __builtin_amdgcn_mfma_f32_16x16x32_bf16(Ah[rt], Bh, C[rt], 0, 0, 0);
            C[rt] = __builtin_amdgcn_mfma_f32_16x16x32_bf16(Al[rt], Bh, C[rt], 0, 0, 0);
            C[rt] = __builtin_amdgcn_mfma_f32_16x16x32_bf16(Ah[rt], Bl, C[rt], 0, 0, 0);
          }
        }
        int dcol = ydh*128 + nt*16 + (lane & 15);
#pragma unroll
        for (int rt = 0; rt < 4; ++rt){
#pragma unroll
          for (int i = 0; i < 4; ++i){
            int b = yc*64 + rt*16 + ((lane>>4)<<2) + i;
            p.Vc[((long)(ya*256 + b)*6 + yn)*256 + dcol] = C[rt][i];
          }
        }
      }
      // attention weights (duty: yn==0 blocks)
      if (yn == 0 && lane < 36){
        int m = lane / 6, n2 = lane % 6;
#pragma unroll
        for (int bb = 0; bb < 4; ++bb){
          int b = ych*32 + wv*4 + bb;
          const float* qp = p.Qs + ((long)(ya*256 + b)*6 + m)*16;
          const float* kp = p.Ks + ((long)(ya*256 + b)*6 + n2)*16;
          float dot = 0.f;
#pragma unroll
          for (int q = 0; q < 16; ++q) dot += qp[q]*kp[q];
          float s = 1.f / (1.f + expf(-dot*0.25f));
          long ob = (((long)ya*T_STEPS + t)*256 + b)*36 + m*6 + n2;
          if (t > 0) s = 0.5f*s + 0.5f*p.aww[ob - 256*36];
          p.aww[ob] = s;
        }
      }
    }
    // out projection for step t-1 (duty: ya==0,yn==1; emu-fp32, A from p.hid)
    if (t > 0 && ya == 0 && yn == 1){
      int rt = wv >> 2, nt = wv & 3;
      int rb = ych*32;
      f32x4 c = {0.f,0.f,0.f,0.f};
      for (int kt = 0; kt < 16; ++kt){
        int b = rb + rt*16 + (lane & 15);
        int kk = kt*32 + ((lane>>4)<<3);        // 0..511
        int m45 = kk >> 8, dd = kk & 255;
        const float* hp = p.hid + ((long)(b*T_STEPS + (t-1))*6 + 4 + m45)*256 + dd;
        bf16x8 ah, al;
#pragma unroll
        for (int j = 0; j < 8; ++j){
          float v = hp[j];
          unsigned short hi = f2bf(v);
          ah[j] = (short)hi;
          al[j] = (short)f2bf(v - bf2f(hi));
        }
        long bo = ((long)(kt*4 + nt)*512) + (long)lane*8;
        bf16x8 bh = *(const bf16x8*)(p.Wouthi + bo);
        bf16x8 bl = *(const bf16x8*)(p.Woutlo + bo);
        c = __builtin_amdgcn_mfma_f32_16x16x32_bf16(ah, bh, c, 0, 0, 0);
        c = __builtin_amdgcn_mfma_f32_16x16x32_bf16(al, bh, c, 0, 0, 0);
        c = __builtin_amdgcn_mfma_f32_16x16x32_bf16(ah, bl, c, 0, 0, 0);
      }
      int o = nt*16 + (lane & 15);
      float bo = p.bout[o];
#pragma unroll
      for (int i = 0; i < 4; ++i){
        int b = rb + rt*16 + ((lane>>4)<<2) + i;
        p.out0[((long)b*T_STEPS + (t-1))*64 + o] = c[i] + bo;
      }
    }

    if (t < T_STEPS) gbar(cnt, rel, ++ep);
  }
}

extern "C" void kernel_launch(void* const* d_in, const int* in_sizes, int n_in,
                              void* d_out, int out_size, void* d_ws, size_t ws_size,
                              hipStream_t stream) {
  (void)in_sizes; (void)n_in; (void)out_size;
  if (ws_size < 16450560) return;

  Params p;
  p.x    = (const float*)d_in[0];
  p.Wt   = (const float*)d_in[1];
  p.Wsn  = (const float*)d_in[2];
  p.Wip  = (const float*)d_in[3];
  p.bip  = (const float*)d_in[4];
  p.U    = (const float*)d_in[5];
  p.Vlr  = (const float*)d_in[6];
  p.bias = (const float*)d_in[7];
  p.WQ   = (const float*)d_in[8];
  p.WK   = (const float*)d_in[9];
  p.WV   = (const float*)d_in[10];
  p.Wout = (const float*)d_in[11];
  p.bout = (const float*)d_in[12];

  float* out = (float*)d_out;
  p.out0 = out;                    // (B,T,O)
  p.hid  = out + 2097152;          // (B,T,M,H)
  p.ain  = out + 52428800;         // (B,T,M,H)
  p.acm  = out + 102760448;        // (B,T,M,H)
  p.aww  = out + 153092096;        // (NH,T,B,M,M)

  char* ws = (char*)d_ws;
  p.bar    = (unsigned*)ws;                         //        0,     1024
  p.WVhi   = (unsigned short*)(ws + 1024);          //  3145728
  p.WVlo   = (unsigned short*)(ws + 3146752);       //  3145728
  p.WQKhi  = (unsigned short*)(ws + 6292480);       //   393216
  p.WQKlo  = (unsigned short*)(ws + 6685696);       //   393216
  p.Wfshi  = (unsigned short*)(ws + 7078912);       //   196608
  p.Wfslo  = (unsigned short*)(ws + 7275520);       //   196608
  p.Wins   = (unsigned short*)(ws + 7472128);       //   196608
  p.Wouthi = (unsigned short*)(ws + 7668736);       //    65536
  p.Woutlo = (unsigned short*)(ws + 7734272);       //    65536
  p.Hhi    = (unsigned short*)(ws + 7799808);       //   786432
  p.Hlo    = (unsigned short*)(ws + 8586240);       //   786432
  p.Qs     = (float*)(ws + 9372672);                //   393216
  p.Ks     = (float*)(ws + 9765888);                //   393216
  p.Vc     = (float*)(ws + 10159104);               //  6291456 -> 16450560

  hipMemsetAsync(d_ws, 0, 1024, stream);
  hipLaunchKernelGGL(prep_fold, dim3(256), dim3(256), 0, stream, p);
  hipLaunchKernelGGL(prep_swz,  dim3(241), dim3(512), 0, stream, p);

  hipFuncSetAttribute((const void*)rim_main,
                      hipFuncAttributeMaxDynamicSharedMemorySize, 160256);
  hipLaunchKernelGGL(rim_main, dim3(NBLK), dim3(512), 160256, stream, p);
}